// Round 3
// baseline (566.780 us; speedup 1.0000x reference)
//
#include <hip/hip_runtime.h>
#include <hip/hip_bf16.h>

typedef __bf16 bf16_t;
typedef __bf16 bf16x8 __attribute__((ext_vector_type(8)));
typedef float  f32x4  __attribute__((ext_vector_type(4)));

#define DEV __device__ __forceinline__

static constexpr int QN    = 8192;
static constexpr int NW    = 5;
static constexpr int D     = 640;
static constexpr int INNER = 512;
static constexpr int MQ    = QN * NW;       // 40960 q-rows
static constexpr int MT    = MQ + 2 * QN;   // 57344 total ln rows

DEV float wredsum(float x) {
#pragma unroll
  for (int o = 32; o > 0; o >>= 1) x += __shfl_xor(x, o, 64);
  return x;
}

// ---------------- LN row statistics: one wave per row ----------------
__global__ __launch_bounds__(256) void ln_stats_kernel(
    const float* __restrict__ q, const float* __restrict__ k,
    const float* __restrict__ v, float* __restrict__ mu,
    float* __restrict__ rstd) {
  int row  = blockIdx.x * 4 + (threadIdx.x >> 6);
  int lane = threadIdx.x & 63;
  const float* src;
  if (row < MQ)            src = q + (size_t)row * D;
  else if (row < MQ + QN)  src = k + (size_t)(row - MQ) * D;
  else                     src = v + (size_t)(row - MQ - QN) * D;
  float s = 0.f, ss = 0.f;
#pragma unroll
  for (int j = 0; j < D / 128; ++j) {
    float2 x = ((const float2*)src)[lane + 64 * j];
    s += x.x + x.y;
    ss += x.x * x.x + x.y * x.y;
  }
  s = wredsum(s); ss = wredsum(ss);
  if (lane == 0) {
    float m   = s * (1.f / D);
    float var = ss * (1.f / D) - m * m;
    mu[row]   = m;
    rstd[row] = rsqrtf(var + 1e-5f);
  }
}

// ------------- transpose + hi/lo bf16 split for weight matrices -------------
__global__ void transpose_split_kernel(const float* __restrict__ src,
                                       bf16_t* __restrict__ dstH,
                                       bf16_t* __restrict__ dstL, int R, int C) {
  int idx = blockIdx.x * 256 + threadIdx.x;
  if (idx >= R * C) return;
  int r = idx / C, c = idx - r * C;
  float x  = src[idx];
  bf16_t h = (bf16_t)x;
  dstH[(size_t)c * R + r] = h;
  dstL[(size_t)c * R + r] = (bf16_t)(x - (float)h);
}

// ---------------- GEMM1 core: LN(x) @ W_in, hi/lo split A and B ----------------
// QPART=false: rows are [k|v] (16384), write Fkv fp32.
// QPART=true : rows are q (40960), fused stats epilogue (no F written).
template <bool QPART>
__global__ __launch_bounds__(256) void gemm1_core(
    const float* __restrict__ q, const float* __restrict__ k,
    const float* __restrict__ v, const float* __restrict__ mu,
    const float* __restrict__ rstd, const float* __restrict__ g,
    const float* __restrict__ b, const bf16_t* __restrict__ BTh,
    const bf16_t* __restrict__ BTl, float* __restrict__ Fkv,
    const float* __restrict__ Fk, float* __restrict__ Sq,
    float* __restrict__ Sqq, float* __restrict__ Sqk) {
  __shared__ bf16_t Ah[64][32];
  __shared__ bf16_t Al[64][32];
  __shared__ bf16_t Bh[64][32];
  __shared__ bf16_t Bl[64][32];
  __shared__ float red[2][64][3];
  const int bm = blockIdx.x, bn = blockIdx.y;
  const int t = threadIdx.x;
  const int lane = t & 63, wid = t >> 6;
  const int wm = (wid >> 1) * 32, wn = (wid & 1) * 32;
  const int lm = lane & 15, quad = lane >> 4;
  const int sr = t >> 2, sc = (t & 3) * 8;

  const int rowL = bm * 64 + sr;  // local row within this part
  const float* aptr;
  int statRow;
  if (QPART) {
    aptr = q + (size_t)rowL * D;
    statRow = rowL;
  } else {
    aptr = (rowL < QN) ? k + (size_t)rowL * D : v + (size_t)(rowL - QN) * D;
    statRow = MQ + rowL;
  }
  const float m_ = mu[statRow], rs_ = rstd[statRow];
  const bf16_t* bhp = BTh + (size_t)(bn * 64 + sr) * D;
  const bf16_t* blp = BTl + (size_t)(bn * 64 + sr) * D;

  f32x4 acc[2][2] = {};

  for (int k0 = 0; k0 < D; k0 += 32) {
    f32x4 xa0 = *(const f32x4*)(aptr + k0 + sc);
    f32x4 xa1 = *(const f32x4*)(aptr + k0 + sc + 4);
    f32x4 xg0 = *(const f32x4*)(g + k0 + sc);
    f32x4 xg1 = *(const f32x4*)(g + k0 + sc + 4);
    f32x4 xb0 = *(const f32x4*)(b + k0 + sc);
    f32x4 xb1 = *(const f32x4*)(b + k0 + sc + 4);
    bf16x8 hi8, lo8;
#pragma unroll
    for (int j = 0; j < 8; ++j) {
      float xv = (j < 4)
          ? ((xa0[j] - m_) * rs_ * xg0[j] + xb0[j])
          : ((xa1[j - 4] - m_) * rs_ * xg1[j - 4] + xb1[j - 4]);
      bf16_t h = (bf16_t)xv;
      hi8[j] = h;
      lo8[j] = (bf16_t)(xv - (float)h);
    }
    *(bf16x8*)&Ah[sr][sc] = hi8;
    *(bf16x8*)&Al[sr][sc] = lo8;
    *(bf16x8*)&Bh[sr][sc] = *(const bf16x8*)(bhp + k0 + sc);
    *(bf16x8*)&Bl[sr][sc] = *(const bf16x8*)(blp + k0 + sc);
    __syncthreads();
    bf16x8 ah0 = *(const bf16x8*)&Ah[wm + lm][quad * 8];
    bf16x8 ah1 = *(const bf16x8*)&Ah[wm + 16 + lm][quad * 8];
    bf16x8 al0 = *(const bf16x8*)&Al[wm + lm][quad * 8];
    bf16x8 al1 = *(const bf16x8*)&Al[wm + 16 + lm][quad * 8];
    bf16x8 bh0 = *(const bf16x8*)&Bh[wn + lm][quad * 8];
    bf16x8 bh1 = *(const bf16x8*)&Bh[wn + 16 + lm][quad * 8];
    bf16x8 bl0 = *(const bf16x8*)&Bl[wn + lm][quad * 8];
    bf16x8 bl1 = *(const bf16x8*)&Bl[wn + 16 + lm][quad * 8];
    acc[0][0] = __builtin_amdgcn_mfma_f32_16x16x32_bf16(ah0, bh0, acc[0][0], 0, 0, 0);
    acc[0][0] = __builtin_amdgcn_mfma_f32_16x16x32_bf16(al0, bh0, acc[0][0], 0, 0, 0);
    acc[0][0] = __builtin_amdgcn_mfma_f32_16x16x32_bf16(ah0, bl0, acc[0][0], 0, 0, 0);
    acc[0][1] = __builtin_amdgcn_mfma_f32_16x16x32_bf16(ah0, bh1, acc[0][1], 0, 0, 0);
    acc[0][1] = __builtin_amdgcn_mfma_f32_16x16x32_bf16(al0, bh1, acc[0][1], 0, 0, 0);
    acc[0][1] = __builtin_amdgcn_mfma_f32_16x16x32_bf16(ah0, bl1, acc[0][1], 0, 0, 0);
    acc[1][0] = __builtin_amdgcn_mfma_f32_16x16x32_bf16(ah1, bh0, acc[1][0], 0, 0, 0);
    acc[1][0] = __builtin_amdgcn_mfma_f32_16x16x32_bf16(al1, bh0, acc[1][0], 0, 0, 0);
    acc[1][0] = __builtin_amdgcn_mfma_f32_16x16x32_bf16(ah1, bl0, acc[1][0], 0, 0, 0);
    acc[1][1] = __builtin_amdgcn_mfma_f32_16x16x32_bf16(ah1, bh1, acc[1][1], 0, 0, 0);
    acc[1][1] = __builtin_amdgcn_mfma_f32_16x16x32_bf16(al1, bh1, acc[1][1], 0, 0, 0);
    acc[1][1] = __builtin_amdgcn_mfma_f32_16x16x32_bf16(ah1, bl1, acc[1][1], 0, 0, 0);
    __syncthreads();
  }

  if (!QPART) {
#pragma unroll
    for (int i = 0; i < 2; ++i)
#pragma unroll
      for (int jj = 0; jj < 2; ++jj)
#pragma unroll
        for (int r = 0; r < 4; ++r) {
          int rr = bm * 64 + wm + i * 16 + quad * 4 + r;
          int cc = bn * 64 + wn + jj * 16 + lm;
          Fkv[(size_t)rr * INNER + cc] = acc[i][jj][r];
        }
  } else {
    // fused stats: per q-row, head bn: S1=sum fq, S2=sum fq^2, S3=sum fq*fk
#pragma unroll
    for (int i = 0; i < 2; ++i)
#pragma unroll
      for (int r = 0; r < 4; ++r) {
        int rowLoc = wm + i * 16 + quad * 4 + r;
        int rowA   = bm * 64 + rowLoc;
        int qi     = rowA / NW;
        float s1 = 0.f, s2 = 0.f, s3 = 0.f;
#pragma unroll
        for (int jj = 0; jj < 2; ++jj) {
          float fq = acc[i][jj][r];
          int cc   = bn * 64 + wn + jj * 16 + lm;
          float fk = Fk[(size_t)qi * INNER + cc];
          s1 += fq; s2 += fq * fq; s3 += fq * fk;
        }
#pragma unroll
        for (int o = 1; o < 16; o <<= 1) {
          s1 += __shfl_xor(s1, o, 64);
          s2 += __shfl_xor(s2, o, 64);
          s3 += __shfl_xor(s3, o, 64);
        }
        if (lm == 0) {
          red[wid & 1][rowLoc][0] = s1;
          red[wid & 1][rowLoc][1] = s2;
          red[wid & 1][rowLoc][2] = s3;
        }
      }
    __syncthreads();
    if (t < 64) {
      int rowA = bm * 64 + t;
      size_t o = (size_t)rowA * 8 + bn;
      Sq[o]  = red[0][t][0] + red[1][t][0];
      Sqq[o] = red[0][t][1] + red[1][t][1];
      Sqk[o] = red[0][t][2] + red[1][t][2];
    }
  }
}

// ---------------- dots: one wave per (qi, head) ----------------
__global__ __launch_bounds__(256) void dots_kernel(
    const float* __restrict__ Fk, const float* __restrict__ Sq,
    const float* __restrict__ Sqq, const float* __restrict__ Sqk,
    const float* __restrict__ vsp, const float* __restrict__ csp,
    float* __restrict__ dots) {
  int gw   = blockIdx.x * 4 + (threadIdx.x >> 6);
  int lane = threadIdx.x & 63;
  int qi = gw >> 3, h = gw & 7;
  float fk  = Fk[(size_t)qi * INNER + h * 64 + lane];
  float sk  = wredsum(fk);
  float skk = wredsum(fk * fk);
  float mk   = sk * (1.f / 64.f);
  float vark = skk * (1.f / 64.f) - mk * mk + 1e-6f;
  float nk   = sqrtf(skk);

  int n = (lane < NW) ? lane : 0;
  size_t si = (size_t)(qi * NW + n) * 8 + h;
  float s1 = Sq[si], s2 = Sqq[si], s3 = Sqk[si];
  float mq   = s1 * (1.f / 64.f);
  float varq = s2 * (1.f / 64.f) - mq * mq + 1e-6f;
  float nq   = sqrtf(s2);
  float cosv = s3 / (nq * nk);
  float vw   = 1.f / (fabsf(vark - varq) + 1e-6f);
  float cov  = (s3 - 64.f * mk * mq) / (64.f + 1e-6f);
  float sg   = 1.f / (1.f + expf(-cov));
  float vwsum = 0.f;
#pragma unroll
  for (int j = 0; j < NW; ++j) vwsum += __shfl(vw, j, 64);
  float dv = cosv + vsp[0] * vw / (vwsum + 1e-6f) + csp[0] * sg;
  if (lane < NW) dots[si] = dv;
}

// ---------------- GEMM2: out = (dots .* f_v) @ W_out + b_out ----------------
// M = MQ, K = INNER, N = D. A formed on the fly (hi/lo split). B pre-split.
__global__ __launch_bounds__(256) void gemm2_kernel(
    const float* __restrict__ Fkv, const float* __restrict__ dots,
    const bf16_t* __restrict__ BTh, const bf16_t* __restrict__ BTl,
    const float* __restrict__ bias, float* __restrict__ out) {
  __shared__ bf16_t Ah[64][32];
  __shared__ bf16_t Al[64][32];
  __shared__ bf16_t Bh[64][32];
  __shared__ bf16_t Bl[64][32];
  const int bm = blockIdx.x, bn = blockIdx.y;
  const int t = threadIdx.x;
  const int lane = t & 63, wid = t >> 6;
  const int wm = (wid >> 1) * 32, wn = (wid & 1) * 32;
  const int lm = lane & 15, quad = lane >> 4;
  const int sr = t >> 2, sc = (t & 3) * 8;

  const int rowA = bm * 64 + sr;
  const int qi = rowA / NW;
  const float* fvrow = Fkv + (size_t)(QN + qi) * INNER;  // v part
  const bf16_t* bhp = BTh + (size_t)(bn * 64 + sr) * INNER;
  const bf16_t* blp = BTl + (size_t)(bn * 64 + sr) * INNER;

  f32x4 acc[2][2] = {};

  for (int k0 = 0; k0 < INNER; k0 += 32) {
    int kk = k0 + sc;
    int h  = kk >> 6;
    float dsc = dots[(size_t)rowA * 8 + h];
    f32x4 f0 = *(const f32x4*)(fvrow + kk);
    f32x4 f1 = *(const f32x4*)(fvrow + kk + 4);
    bf16x8 hi8, lo8;
#pragma unroll
    for (int j = 0; j < 8; ++j) {
      float y  = dsc * ((j < 4) ? f0[j] : f1[j - 4]);
      bf16_t h2 = (bf16_t)y;
      hi8[j] = h2;
      lo8[j] = (bf16_t)(y - (float)h2);
    }
    *(bf16x8*)&Ah[sr][sc] = hi8;
    *(bf16x8*)&Al[sr][sc] = lo8;
    *(bf16x8*)&Bh[sr][sc] = *(const bf16x8*)(bhp + k0 + sc);
    *(bf16x8*)&Bl[sr][sc] = *(const bf16x8*)(blp + k0 + sc);
    __syncthreads();
    bf16x8 ah0 = *(const bf16x8*)&Ah[wm + lm][quad * 8];
    bf16x8 ah1 = *(const bf16x8*)&Ah[wm + 16 + lm][quad * 8];
    bf16x8 al0 = *(const bf16x8*)&Al[wm + lm][quad * 8];
    bf16x8 al1 = *(const bf16x8*)&Al[wm + 16 + lm][quad * 8];
    bf16x8 bh0 = *(const bf16x8*)&Bh[wn + lm][quad * 8];
    bf16x8 bh1 = *(const bf16x8*)&Bh[wn + 16 + lm][quad * 8];
    bf16x8 bl0 = *(const bf16x8*)&Bl[wn + lm][quad * 8];
    bf16x8 bl1 = *(const bf16x8*)&Bl[wn + 16 + lm][quad * 8];
    acc[0][0] = __builtin_amdgcn_mfma_f32_16x16x32_bf16(ah0, bh0, acc[0][0], 0, 0, 0);
    acc[0][0] = __builtin_amdgcn_mfma_f32_16x16x32_bf16(al0, bh0, acc[0][0], 0, 0, 0);
    acc[0][0] = __builtin_amdgcn_mfma_f32_16x16x32_bf16(ah0, bl0, acc[0][0], 0, 0, 0);
    acc[0][1] = __builtin_amdgcn_mfma_f32_16x16x32_bf16(ah0, bh1, acc[0][1], 0, 0, 0);
    acc[0][1] = __builtin_amdgcn_mfma_f32_16x16x32_bf16(al0, bh1, acc[0][1], 0, 0, 0);
    acc[0][1] = __builtin_amdgcn_mfma_f32_16x16x32_bf16(ah0, bl1, acc[0][1], 0, 0, 0);
    acc[1][0] = __builtin_amdgcn_mfma_f32_16x16x32_bf16(ah1, bh0, acc[1][0], 0, 0, 0);
    acc[1][0] = __builtin_amdgcn_mfma_f32_16x16x32_bf16(al1, bh0, acc[1][0], 0, 0, 0);
    acc[1][0] = __builtin_amdgcn_mfma_f32_16x16x32_bf16(ah1, bl0, acc[1][0], 0, 0, 0);
    acc[1][1] = __builtin_amdgcn_mfma_f32_16x16x32_bf16(ah1, bh1, acc[1][1], 0, 0, 0);
    acc[1][1] = __builtin_amdgcn_mfma_f32_16x16x32_bf16(al1, bh1, acc[1][1], 0, 0, 0);
    acc[1][1] = __builtin_amdgcn_mfma_f32_16x16x32_bf16(ah1, bl1, acc[1][1], 0, 0, 0);
    __syncthreads();
  }
#pragma unroll
  for (int i = 0; i < 2; ++i)
#pragma unroll
    for (int jj = 0; jj < 2; ++jj)
#pragma unroll
      for (int r = 0; r < 4; ++r) {
        int rr = bm * 64 + wm + i * 16 + quad * 4 + r;
        int cc = bn * 64 + wn + jj * 16 + lm;
        out[(size_t)rr * D + cc] = acc[i][jj][r] + bias[cc];
      }
}

extern "C" void kernel_launch(void* const* d_in, const int* in_sizes, int n_in,
                              void* d_out, int out_size, void* d_ws,
                              size_t ws_size, hipStream_t stream) {
  const float* q    = (const float*)d_in[0];
  const float* k    = (const float*)d_in[1];
  const float* v    = (const float*)d_in[2];
  const float* g    = (const float*)d_in[3];
  const float* b    = (const float*)d_in[4];
  const float* Win  = (const float*)d_in[5];
  const float* Wout = (const float*)d_in[6];
  const float* bout = (const float*)d_in[7];
  const float* vsp  = (const float*)d_in[8];
  const float* csp  = (const float*)d_in[9];
  float* out = (float*)d_out;

  char* w = (char*)d_ws;
  float* Fkv     = (float*)w;  w += (size_t)(2 * QN) * INNER * 4;  // k rows then v rows
  float* Sq      = (float*)w;  w += (size_t)MQ * 8 * 4;
  float* Sqq     = (float*)w;  w += (size_t)MQ * 8 * 4;
  float* Sqk     = (float*)w;  w += (size_t)MQ * 8 * 4;
  float* dots    = (float*)w;  w += (size_t)MQ * 8 * 4;
  float* mu      = (float*)w;  w += (size_t)MT * 4;
  float* rstd    = (float*)w;  w += (size_t)MT * 4;
  bf16_t* WinTh  = (bf16_t*)w; w += (size_t)INNER * D * 2;
  bf16_t* WinTl  = (bf16_t*)w; w += (size_t)INNER * D * 2;
  bf16_t* WoutTh = (bf16_t*)w; w += (size_t)D * INNER * 2;
  bf16_t* WoutTl = (bf16_t*)w; w += (size_t)D * INNER * 2;
  // total ~43 MB

  ln_stats_kernel<<<dim3(MT / 4), dim3(256), 0, stream>>>(q, k, v, mu, rstd);
  transpose_split_kernel<<<dim3((D * INNER + 255) / 256), dim3(256), 0, stream>>>(
      Win, WinTh, WinTl, D, INNER);
  transpose_split_kernel<<<dim3((INNER * D + 255) / 256), dim3(256), 0, stream>>>(
      Wout, WoutTh, WoutTl, INNER, D);
  // k/v projection -> Fkv
  gemm1_core<false><<<dim3(2 * QN / 64, INNER / 64), dim3(256), 0, stream>>>(
      q, k, v, mu, rstd, g, b, WinTh, WinTl, Fkv, nullptr, nullptr, nullptr,
      nullptr);
  // q projection with fused stats (reads k part of Fkv)
  gemm1_core<true><<<dim3(MQ / 64, INNER / 64), dim3(256), 0, stream>>>(
      q, k, v, mu, rstd, g, b, WinTh, WinTl, nullptr, Fkv, Sq, Sqq, Sqk);
  dots_kernel<<<dim3(QN * 8 / 4), dim3(256), 0, stream>>>(
      Fkv, Sq, Sqq, Sqk, vsp, csp, dots);
  gemm2_kernel<<<dim3(MQ / 64, D / 64), dim3(256), 0, stream>>>(
      Fkv, dots, WoutTh, WoutTl, bout, out);
}

// Round 4
// 483.990 us; speedup vs baseline: 1.1711x; 1.1711x over previous
//
#include <hip/hip_runtime.h>
#include <hip/hip_bf16.h>

typedef __bf16 bf16_t;
typedef __bf16 bf16x8 __attribute__((ext_vector_type(8)));
typedef float  f32x4  __attribute__((ext_vector_type(4)));

#define DEV __device__ __forceinline__

static constexpr int QN    = 8192;
static constexpr int NW    = 5;
static constexpr int D     = 640;
static constexpr int INNER = 512;
static constexpr int MQ    = QN * NW;     // 40960 q rows
static constexpr int QHALF = MQ / 2;      // 20480

DEV float wredsum(float x) {
#pragma unroll
  for (int o = 32; o > 0; o >>= 1) x += __shfl_xor(x, o, 64);
  return x;
}

// async 16B-per-lane global->LDS copy; LDS dest = wave-uniform base + lane*16
DEV void gl_lds16(const bf16_t* g, bf16_t* l) {
  __builtin_amdgcn_global_load_lds(
      (const __attribute__((address_space(1))) unsigned int*)g,
      (__attribute__((address_space(3))) unsigned int*)l, 16, 0, 0);
}

// ---------------- LN + hi/lo bf16 split, one wave per row ----------------
// Writes Ah/Al rows 0..nrows-1 for global rows row0..row0+nrows-1.
__global__ __launch_bounds__(256) void ln_split_kernel(
    const float* __restrict__ q, const float* __restrict__ k,
    const float* __restrict__ v, const float* __restrict__ g,
    const float* __restrict__ b, bf16_t* __restrict__ Ah,
    bf16_t* __restrict__ Al, int row0) {
  int lr   = blockIdx.x * 4 + (threadIdx.x >> 6);
  int lane = threadIdx.x & 63;
  int rg   = row0 + lr;
  const float* src = (rg < MQ) ? q + (size_t)rg * D
                   : (rg < MQ + QN) ? k + (size_t)(rg - MQ) * D
                   : v + (size_t)(rg - MQ - QN) * D;
  float2 x[5];
  float s = 0.f, ss = 0.f;
#pragma unroll
  for (int j = 0; j < 5; ++j) {
    x[j] = ((const float2*)src)[lane + 64 * j];
    s  += x[j].x + x[j].y;
    ss += x[j].x * x[j].x + x[j].y * x[j].y;
  }
  s = wredsum(s); ss = wredsum(ss);
  float m  = s * (1.f / D);
  float rs = rsqrtf(ss * (1.f / D) - m * m + 1e-5f);
#pragma unroll
  for (int j = 0; j < 5; ++j) {
    float2 gg = ((const float2*)g)[lane + 64 * j];
    float2 bb = ((const float2*)b)[lane + 64 * j];
    float xn0 = (x[j].x - m) * rs * gg.x + bb.x;
    float xn1 = (x[j].y - m) * rs * gg.y + bb.y;
    bf16_t h0 = (bf16_t)xn0, h1 = (bf16_t)xn1;
    union { bf16_t bb2[2]; unsigned u; } ph, pl;
    ph.bb2[0] = h0; ph.bb2[1] = h1;
    pl.bb2[0] = (bf16_t)(xn0 - (float)h0);
    pl.bb2[1] = (bf16_t)(xn1 - (float)h1);
    ((unsigned*)(Ah + (size_t)lr * D))[lane + 64 * j] = ph.u;
    ((unsigned*)(Al + (size_t)lr * D))[lane + 64 * j] = pl.u;
  }
}

// ------------- transpose + hi/lo bf16 split for weight matrices -------------
__global__ void transpose_split_kernel(const float* __restrict__ src,
                                       bf16_t* __restrict__ dstH,
                                       bf16_t* __restrict__ dstL, int R, int C) {
  int idx = blockIdx.x * 256 + threadIdx.x;
  if (idx >= R * C) return;
  int r = idx / C, c = idx - r * C;
  float x  = src[idx];
  bf16_t h = (bf16_t)x;
  dstH[(size_t)c * R + r] = h;
  dstL[(size_t)c * R + r] = (bf16_t)(x - (float)h);
}

// ---------------- GEMM1: 128x128 tile, BK=32, global_load_lds ----------------
// A (pre-split LN rows) [rows][640], B = Win^T split [512][640].
// MODE 0: rows are [k|v] local 0..16383; k-blocks (bm<64) 3-term, v 1-term; write Fkv.
// MODE 1: rows are q (local half), 3-term; fused stats epilogue reading Fk.
template <int MODE>
__global__ __launch_bounds__(256) void gemm1_kernel(
    const bf16_t* __restrict__ Ah, const bf16_t* __restrict__ Al,
    const bf16_t* __restrict__ Bh, const bf16_t* __restrict__ Bl,
    float* __restrict__ Fkv, const float* __restrict__ Fk,
    float* __restrict__ Sq, float* __restrict__ Sqq,
    float* __restrict__ Sqk, int qrow0) {
  __shared__ __align__(16) bf16_t AhS[128 * 32];
  __shared__ __align__(16) bf16_t AlS[128 * 32];
  __shared__ __align__(16) bf16_t BhS[128 * 32];
  __shared__ __align__(16) bf16_t BlS[128 * 32];
  const int bn = blockIdx.x & 3, bm = blockIdx.x >> 2;
  const int t = threadIdx.x, lane = t & 63, wid = t >> 6;
  const int wr = wid >> 1, wc = wid & 1;
  const int lm = lane & 15, quad = lane >> 4;
  const bool T3 = (MODE == 1) || (bm < 64);
  const size_t arow0 = (size_t)bm * 128;
  const size_t brow0 = (size_t)bn * 128;
  const int cb = wid * 2;

  f32x4 acc[4][4] = {};

  for (int k0 = 0; k0 < 640; k0 += 32) {
#pragma unroll
    for (int tt = 0; tt < 2; ++tt) {
      int chunk = (cb + tt) * 64 + lane;
      int r = chunk >> 2, c8 = (chunk & 3) * 8;
      gl_lds16(Ah + (arow0 + r) * 640 + k0 + c8, &AhS[(cb + tt) * 512]);
      gl_lds16(Bh + (brow0 + r) * 640 + k0 + c8, &BhS[(cb + tt) * 512]);
      if (T3) {
        gl_lds16(Al + (arow0 + r) * 640 + k0 + c8, &AlS[(cb + tt) * 512]);
        gl_lds16(Bl + (brow0 + r) * 640 + k0 + c8, &BlS[(cb + tt) * 512]);
      }
    }
    __syncthreads();
    bf16x8 ah[4], bh[4], al[4], bl[4];
#pragma unroll
    for (int i = 0; i < 4; ++i) {
      ah[i] = *(const bf16x8*)&AhS[(wr * 64 + i * 16 + lm) * 32 + quad * 8];
      bh[i] = *(const bf16x8*)&BhS[(wc * 64 + i * 16 + lm) * 32 + quad * 8];
    }
    if (T3) {
#pragma unroll
      for (int i = 0; i < 4; ++i) {
        al[i] = *(const bf16x8*)&AlS[(wr * 64 + i * 16 + lm) * 32 + quad * 8];
        bl[i] = *(const bf16x8*)&BlS[(wc * 64 + i * 16 + lm) * 32 + quad * 8];
      }
    }
#pragma unroll
    for (int mi = 0; mi < 4; ++mi)
#pragma unroll
      for (int nj = 0; nj < 4; ++nj) {
        acc[mi][nj] =
            __builtin_amdgcn_mfma_f32_16x16x32_bf16(ah[mi], bh[nj], acc[mi][nj], 0, 0, 0);
        if (T3) {
          acc[mi][nj] =
              __builtin_amdgcn_mfma_f32_16x16x32_bf16(al[mi], bh[nj], acc[mi][nj], 0, 0, 0);
          acc[mi][nj] =
              __builtin_amdgcn_mfma_f32_16x16x32_bf16(ah[mi], bl[nj], acc[mi][nj], 0, 0, 0);
        }
      }
    __syncthreads();
  }

  if (MODE == 0) {
#pragma unroll
    for (int mi = 0; mi < 4; ++mi)
#pragma unroll
      for (int nj = 0; nj < 4; ++nj)
#pragma unroll
        for (int r = 0; r < 4; ++r) {
          int row = bm * 128 + wr * 64 + mi * 16 + quad * 4 + r;
          int col = bn * 128 + wc * 64 + nj * 16 + lm;
          Fkv[(size_t)row * INNER + col] = acc[mi][nj][r];
        }
  } else {
    const int head = bn * 2 + wc;
#pragma unroll
    for (int mi = 0; mi < 4; ++mi)
#pragma unroll
      for (int r = 0; r < 4; ++r) {
        int rowA = qrow0 + bm * 128 + wr * 64 + mi * 16 + quad * 4 + r;
        int qi   = (unsigned)rowA / NW;
        float s1 = 0.f, s2 = 0.f, s3 = 0.f;
#pragma unroll
        for (int nj = 0; nj < 4; ++nj) {
          float fq = acc[mi][nj][r];
          float fk = Fk[(size_t)qi * INNER + head * 64 + nj * 16 + lm];
          s1 += fq; s2 += fq * fq; s3 += fq * fk;
        }
#pragma unroll
        for (int o = 1; o < 16; o <<= 1) {
          s1 += __shfl_xor(s1, o, 64);
          s2 += __shfl_xor(s2, o, 64);
          s3 += __shfl_xor(s3, o, 64);
        }
        if (lm == 0) {
          size_t o = (size_t)rowA * 8 + head;
          Sq[o] = s1; Sqq[o] = s2; Sqk[o] = s3;
        }
      }
  }
}

// ---------------- dots + Y = dots .* f_v (bf16), fused ----------------
__global__ __launch_bounds__(256) void dots_y_kernel(
    const float* __restrict__ Fkv, const float* __restrict__ Sq,
    const float* __restrict__ Sqq, const float* __restrict__ Sqk,
    const float* __restrict__ vsp, const float* __restrict__ csp,
    bf16_t* __restrict__ Yh) {
  int wv   = blockIdx.x * 4 + (threadIdx.x >> 6);
  int lane = threadIdx.x & 63;
  int qi = wv >> 3, h = wv & 7;
  float fk = Fkv[(size_t)qi * INNER + h * 64 + lane];
  float fv = Fkv[(size_t)(QN + qi) * INNER + h * 64 + lane];
  float sk  = wredsum(fk);
  float skk = wredsum(fk * fk);
  float mk   = sk * (1.f / 64.f);
  float vark = skk * (1.f / 64.f) - mk * mk + 1e-6f;
  float nk   = sqrtf(skk);

  int n = (lane < NW) ? lane : 0;
  size_t si = (size_t)(qi * NW + n) * 8 + h;
  float s1 = Sq[si], s2 = Sqq[si], s3 = Sqk[si];
  float mq   = s1 * (1.f / 64.f);
  float varq = s2 * (1.f / 64.f) - mq * mq + 1e-6f;
  float nq   = sqrtf(s2);
  float cosv = s3 / (nq * nk);
  float vw   = 1.f / (fabsf(vark - varq) + 1e-6f);
  float cov  = (s3 - 64.f * mk * mq) / (64.f + 1e-6f);
  float sg   = 1.f / (1.f + expf(-cov));
  float vwsum = 0.f;
#pragma unroll
  for (int j = 0; j < NW; ++j) vwsum += __shfl(vw, j, 64);
  float dv = cosv + vsp[0] * vw / (vwsum + 1e-6f) + csp[0] * sg;
#pragma unroll
  for (int j = 0; j < NW; ++j) {
    float dvj = __shfl(dv, j, 64);
    Yh[(size_t)(qi * NW + j) * INNER + h * 64 + lane] = (bf16_t)(dvj * fv);
  }
}

// ---------------- GEMM2: out = Y @ W_out + b_out (1-term bf16) ----------------
__global__ __launch_bounds__(256) void gemm2_kernel(
    const bf16_t* __restrict__ Yh, const bf16_t* __restrict__ Bh,
    const float* __restrict__ bias, float* __restrict__ out) {
  __shared__ __align__(16) bf16_t AS[128 * 32];
  __shared__ __align__(16) bf16_t BS[128 * 32];
  const int bn = blockIdx.x % 5, bm = blockIdx.x / 5;
  const int t = threadIdx.x, lane = t & 63, wid = t >> 6;
  const int wr = wid >> 1, wc = wid & 1;
  const int lm = lane & 15, quad = lane >> 4;
  const size_t arow0 = (size_t)bm * 128;
  const size_t brow0 = (size_t)bn * 128;
  const int cb = wid * 2;

  f32x4 acc[4][4] = {};

  for (int k0 = 0; k0 < INNER; k0 += 32) {
#pragma unroll
    for (int tt = 0; tt < 2; ++tt) {
      int chunk = (cb + tt) * 64 + lane;
      int r = chunk >> 2, c8 = (chunk & 3) * 8;
      gl_lds16(Yh + (arow0 + r) * INNER + k0 + c8, &AS[(cb + tt) * 512]);
      gl_lds16(Bh + (brow0 + r) * INNER + k0 + c8, &BS[(cb + tt) * 512]);
    }
    __syncthreads();
    bf16x8 a[4], b[4];
#pragma unroll
    for (int i = 0; i < 4; ++i) {
      a[i] = *(const bf16x8*)&AS[(wr * 64 + i * 16 + lm) * 32 + quad * 8];
      b[i] = *(const bf16x8*)&BS[(wc * 64 + i * 16 + lm) * 32 + quad * 8];
    }
#pragma unroll
    for (int mi = 0; mi < 4; ++mi)
#pragma unroll
      for (int nj = 0; nj < 4; ++nj)
        acc[mi][nj] =
            __builtin_amdgcn_mfma_f32_16x16x32_bf16(a[mi], b[nj], acc[mi][nj], 0, 0, 0);
    __syncthreads();
  }
#pragma unroll
  for (int mi = 0; mi < 4; ++mi)
#pragma unroll
    for (int nj = 0; nj < 4; ++nj) {
      float bia = bias[bn * 128 + wc * 64 + nj * 16 + lm];
#pragma unroll
      for (int r = 0; r < 4; ++r) {
        int row = bm * 128 + wr * 64 + mi * 16 + quad * 4 + r;
        int col = bn * 128 + wc * 64 + nj * 16 + lm;
        out[(size_t)row * D + col] = acc[mi][nj][r] + bia;
      }
    }
}

extern "C" void kernel_launch(void* const* d_in, const int* in_sizes, int n_in,
                              void* d_out, int out_size, void* d_ws,
                              size_t ws_size, hipStream_t stream) {
  const float* q    = (const float*)d_in[0];
  const float* k    = (const float*)d_in[1];
  const float* v    = (const float*)d_in[2];
  const float* g    = (const float*)d_in[3];
  const float* b    = (const float*)d_in[4];
  const float* Win  = (const float*)d_in[5];
  const float* Wout = (const float*)d_in[6];
  const float* bout = (const float*)d_in[7];
  const float* vsp  = (const float*)d_in[8];
  const float* csp  = (const float*)d_in[9];
  float* out = (float*)d_out;

  char* w = (char*)d_ws;
  float* Fkv     = (float*)w;  w += (size_t)(2 * QN) * INNER * 4;   // 33.55 MB
  float* Sq      = (float*)w;  w += (size_t)MQ * 8 * 4;             // 1.31 MB
  float* Sqq     = (float*)w;  w += (size_t)MQ * 8 * 4;
  float* Sqk     = (float*)w;  w += (size_t)MQ * 8 * 4;
  bf16_t* Ah     = (bf16_t*)w; w += (size_t)QHALF * D * 2;          // 26.2 MB
  bf16_t* Al     = (bf16_t*)w; w += (size_t)QHALF * D * 2;          // 26.2 MB
  bf16_t* Yh     = (bf16_t*)w; w += (size_t)MQ * INNER * 2;         // 41.9 MB
  bf16_t* WinTh  = (bf16_t*)w; w += (size_t)INNER * D * 2;
  bf16_t* WinTl  = (bf16_t*)w; w += (size_t)INNER * D * 2;
  bf16_t* WoutTh = (bf16_t*)w; w += (size_t)D * INNER * 2;
  bf16_t* WoutTl = (bf16_t*)w; w += (size_t)D * INNER * 2;
  // total ~134.5 MB

  transpose_split_kernel<<<dim3((D * INNER + 255) / 256), dim3(256), 0, stream>>>(
      Win, WinTh, WinTl, D, INNER);
  transpose_split_kernel<<<dim3((INNER * D + 255) / 256), dim3(256), 0, stream>>>(
      Wout, WoutTh, WoutTl, INNER, D);

  // --- k/v rows: LN-split then project -> Fkv (k 3-term, v 1-term) ---
  ln_split_kernel<<<dim3(2 * QN / 4), dim3(256), 0, stream>>>(
      q, k, v, g, b, Ah, Al, MQ);
  gemm1_kernel<0><<<dim3((2 * QN / 128) * 4), dim3(256), 0, stream>>>(
      Ah, Al, WinTh, WinTl, Fkv, nullptr, nullptr, nullptr, nullptr, 0);

  // --- q rows (two halves reusing the split buffer): fused stats ---
  ln_split_kernel<<<dim3(QHALF / 4), dim3(256), 0, stream>>>(
      q, k, v, g, b, Ah, Al, 0);
  gemm1_kernel<1><<<dim3((QHALF / 128) * 4), dim3(256), 0, stream>>>(
      Ah, Al, WinTh, WinTl, nullptr, Fkv, Sq, Sqq, Sqk, 0);
  ln_split_kernel<<<dim3(QHALF / 4), dim3(256), 0, stream>>>(
      q, k, v, g, b, Ah, Al, QHALF);
  gemm1_kernel<1><<<dim3((QHALF / 128) * 4), dim3(256), 0, stream>>>(
      Ah, Al, WinTh, WinTl, nullptr, Fkv, Sq, Sqq, Sqk, QHALF);

  // --- dots + Y, then output GEMM ---
  dots_y_kernel<<<dim3(QN * 8 / 4), dim3(256), 0, stream>>>(
      Fkv, Sq, Sqq, Sqk, vsp, csp, Yh);
  gemm2_kernel<<<dim3((MQ / 128) * 5), dim3(256), 0, stream>>>(
      Yh, WoutTh, bout, out);
}